// Round 22
// baseline (2648.837 us; speedup 1.0000x reference)
//
#include <hip/hip_runtime.h>
#include <cstddef>

#define BATCH 8
#define NPTS 8192
#define NFEAT 64
#define NPOINT 2048
#define NSAMPLE 32

// -- plain-rounded ops, contraction-proof (verified bit-exact R4-R21)
__device__ __forceinline__ float sq_nc(float a) {
    float r = a * a;
    asm volatile("" : "+v"(r));
    return r;
}
__device__ __forceinline__ float mul_nc(float a, float b) {
    float r = a * b;
    asm volatile("" : "+v"(r));
    return r;
}

// DPP-based fmax mix (VALU ~5cyc). Controls: 0xB1 xor1, 0x4E xor2,
// 0x141 row_half_mirror, 0x140 row_mirror, 0x142 bcast15, 0x143 bcast31.
template <int CTRL>
__device__ __forceinline__ float dppmax(float v) {
    int r = __builtin_amdgcn_mov_dpp(__float_as_int(v), CTRL, 0xF, 0xF, true);
    return fmaxf(v, __int_as_float(r));
}

// ---------------------------------------------------------------------------
// FUSED fps + f1 kernel. R21-EXACT (best measured: 1637us steady-state).
// ---------------------------------------------------------------------------
__global__ __launch_bounds__(512) void fps_f1_kernel(const float* __restrict__ xyz,
                                                     const float* __restrict__ features,
                                                     const float* __restrict__ W1,
                                                     float* __restrict__ F1,
                                                     float* __restrict__ newxyz) {
    extern __shared__ float lds[];
    const int tid = threadIdx.x;

    if (blockIdx.x >= 8) {
        // ================= F1 part: 128 points per block =================
        const int lane = tid & 63;
        const int chunk = (tid >> 6) & 3;              // 0..3 (16 ch each)
        const int sub = tid >> 8;                      // 0..1
        const int fblk = blockIdx.x - 8;               // 0..511
        const int b = fblk >> 6;                       // 64 blocks/batch
        const int n = ((fblk & 63) << 7) + (sub << 6) + lane;
        const float* fb = features + (size_t)b * NFEAT * NPTS + n;
        const float* wbase = W1 + 3 * 64 + chunk * 16;

        float acc[16];
#pragma unroll
        for (int i = 0; i < 16; ++i) acc[i] = 0.0f;

#pragma unroll 4
        for (int cp = 0; cp < 64; ++cp) {
            float f = fb[(size_t)cp * NPTS];
            const float4* w = reinterpret_cast<const float4*>(wbase + (size_t)cp * 64);
#pragma unroll
            for (int c4 = 0; c4 < 4; ++c4) {
                float4 ww = w[c4];
                acc[c4 * 4 + 0] += f * ww.x;
                acc[c4 * 4 + 1] += f * ww.y;
                acc[c4 * 4 + 2] += f * ww.z;
                acc[c4 * 4 + 3] += f * ww.w;
            }
        }
        float* o = F1 + ((size_t)b * NPTS + n) * 64 + chunk * 16;
#pragma unroll
        for (int c4 = 0; c4 < 4; ++c4) {
            float4 v;
            v.x = acc[c4 * 4 + 0]; v.y = acc[c4 * 4 + 1];
            v.z = acc[c4 * 4 + 2]; v.w = acc[c4 * 4 + 3];
            *reinterpret_cast<float4*>(o + c4 * 4) = v;
        }
        return;
    }

    // ================= FPS part =================
    float* sx = lds;
    float* sy = lds + NPTS;
    float* sz = lds + 2 * NPTS;
    __shared__ alignas(16) unsigned long long redp[2][8];

    const int b = blockIdx.x;
    const int lane = tid & 63;
    const int wid = tid >> 6;
    const float* xb = xyz + (size_t)b * NPTS * 3;

    for (int i = tid; i < NPTS; i += 512) {
        sx[i] = xb[i * 3 + 0];
        sy[i] = xb[i * 3 + 1];
        sz[i] = xb[i * 3 + 2];
    }
    __syncthreads();

    float mx[16], my_[16], mz[16], md[16];
    const int base = tid * 16;
#pragma unroll
    for (int j = 0; j < 16; ++j) {
        mx[j] = sx[base + j];
        my_[j] = sy[base + j];
        mz[j] = sz[base + j];
        md[j] = INFINITY;
    }

    if (tid == 0) {
        newxyz[(size_t)b * NPOINT * 3 + 0] = sx[0];
        newxyz[(size_t)b * NPOINT * 3 + 1] = sy[0];
        newxyz[(size_t)b * NPOINT * 3 + 2] = sz[0];
    }
    float xl = sx[0], yl = sy[0], zl = sz[0];
    int par = 0;

    for (int it = 1; it < NPOINT; ++it) {
        float bv = -1.0f;
        int bi = 0;
#pragma unroll
        for (int j = 0; j < 16; ++j) {
            float dx = mx[j] - xl;
            float dy = my_[j] - yl;
            float dz = mz[j] - zl;
            float d = (sq_nc(dx) + sq_nc(dy)) + sq_nc(dz);
            float m = fminf(md[j], d);
            md[j] = m;
            if (m > bv) { bv = m; bi = base + j; }
        }

        float wv = bv;
        wv = dppmax<0xB1>(wv);
        wv = dppmax<0x4E>(wv);
        wv = dppmax<0x141>(wv);
        wv = dppmax<0x140>(wv);
        wv = dppmax<0x142>(wv);
        wv = dppmax<0x143>(wv);
        float wvf = __int_as_float(__builtin_amdgcn_readlane(__float_as_int(wv), 63));

        unsigned long long msk = __ballot(bv == wvf);
        int src = __builtin_ctzll(msk);
        if (lane == src)
            redp[par][wid] = ((unsigned long long)__float_as_uint(wvf) << 32) |
                             (unsigned int)(~(unsigned int)bi);
        __syncthreads();

        const ulonglong2* rp = (const ulonglong2*)redp[par];
        ulonglong2 r0 = rp[0], r1 = rp[1], r2 = rp[2], r3 = rp[3];
        unsigned long long m0 = (r0.x > r0.y) ? r0.x : r0.y;
        unsigned long long m1 = (r1.x > r1.y) ? r1.x : r1.y;
        unsigned long long m2 = (r2.x > r2.y) ? r2.x : r2.y;
        unsigned long long m3 = (r3.x > r3.y) ? r3.x : r3.y;
        m0 = (m1 > m0) ? m1 : m0;
        m2 = (m3 > m2) ? m3 : m2;
        m0 = (m2 > m0) ? m2 : m0;
        const int fi = (int)(~(unsigned int)m0);

        xl = sx[fi]; yl = sy[fi]; zl = sz[fi];
        if (tid == 0) {
            size_t o = (size_t)b * NPOINT * 3 + (size_t)it * 3;
            newxyz[o + 0] = xl;
            newxyz[o + 1] = yl;
            newxyz[o + 2] = zl;
        }
        par ^= 1;
    }
}

// ---------------------------------------------------------------------------
// Ball query. UNCHANGED (verified R5-R21).
// ---------------------------------------------------------------------------
__global__ __launch_bounds__(64) void ball_kernel(const float* __restrict__ xyz,
                                                  const float* __restrict__ newxyz,
                                                  int* __restrict__ ballidx) {
    extern __shared__ float4 s4[];                       // 8192 float4 = 128KB
    const int b = blockIdx.y;
    const int s = blockIdx.x * 64 + threadIdx.x;
    const float* xb = xyz + (size_t)b * NPTS * 3;
    for (int i = threadIdx.x; i < NPTS; i += 64) {
        float x = xb[i * 3 + 0], y = xb[i * 3 + 1], z = xb[i * 3 + 2];
        float sq = (sq_nc(x) + sq_nc(y)) + sq_nc(z);
        s4[i] = make_float4(x, y, z, sq);
    }
    __syncthreads();

    const int sIdx = b * NPOINT + s;
    float cx = newxyz[(size_t)sIdx * 3 + 0];
    float cy = newxyz[(size_t)sIdx * 3 + 1];
    float cz = newxyz[(size_t)sIdx * 3 + 2];
    float cq = (sq_nc(cx) + sq_nc(cy)) + sq_nc(cz);

    int* ob = ballidx + (size_t)sIdx * NSAMPLE;
    int cnt = 0;
    int first = 0;
#pragma unroll 4
    for (int n = 0; n < NPTS; ++n) {
        float4 p = s4[n];
        float dot = __fmaf_rn(cz, p.z, __fmaf_rn(cy, p.y, __fmul_rn(cx, p.x)));
        float d2 = (cq + p.w) - mul_nc(2.0f, dot);
        if (d2 < 0.04f && cnt < NSAMPLE) {
            ob[cnt] = n;
            if (cnt == 0) first = n;
            ++cnt;
        }
    }
    for (int j = cnt; j < NSAMPLE; ++j) ob[j] = first;
}

// ---------------------------------------------------------------------------
// Fused grouped-MLP + max-pool — UNTRIED CELL: h1/h2 in REGISTERS (no hbuf),
// weights in 50.9KB LDS (broadcast reads ~120cyc vs L2 ~200cyc). Static LDS
// -> compiler knows 3 blocks/CU (12 waves); __launch_bounds__(256,3) pins the
// VGPR budget (~170) so the 64-float h arrays stay register-resident.
// All h indices compile-time (inner loops fully unrolled).
// ---------------------------------------------------------------------------
__global__ __launch_bounds__(256, 3) void mlp_kernel(const float* __restrict__ xyz,
                                                     const float* __restrict__ W1,
                                                     const float* __restrict__ b1,
                                                     const float* __restrict__ W2,
                                                     const float* __restrict__ b2,
                                                     const float* __restrict__ W3,
                                                     const float* __restrict__ b3,
                                                     const float* __restrict__ F1,
                                                     const int* __restrict__ ballidx,
                                                     const float* __restrict__ newxyz,
                                                     float* __restrict__ outF) {
    __shared__ float w2s[4096];
    __shared__ float w3s[8192];
    __shared__ float w1s[192];
    __shared__ float b1s[64], b2s[64], b3s[128];

    const int tid = threadIdx.x;
    const int k = tid & 31;
    const int sIdx = blockIdx.x * 8 + (tid >> 5);      // 0 .. BATCH*NPOINT-1
    const int b = sIdx >> 11;
    const int s = sIdx & (NPOINT - 1);

    // ---- stage weights/biases once per block (coalesced float4)
    for (int i = tid; i < 1024; i += 256)
        reinterpret_cast<float4*>(w2s)[i] = reinterpret_cast<const float4*>(W2)[i];
    for (int i = tid; i < 2048; i += 256)
        reinterpret_cast<float4*>(w3s)[i] = reinterpret_cast<const float4*>(W3)[i];
    if (tid < 192) w1s[tid] = W1[tid];
    if (tid < 64)  { b1s[tid] = b1[tid]; b2s[tid] = b2[tid]; }
    if (tid < 128) b3s[tid] = b3[tid];

    const int p = ballidx[(size_t)sIdx * NSAMPLE + k];
    const float* xb = xyz + (size_t)b * NPTS * 3;
    float rx = xb[p * 3 + 0] - newxyz[(size_t)sIdx * 3 + 0];
    float ry = xb[p * 3 + 1] - newxyz[(size_t)sIdx * 3 + 1];
    float rz = xb[p * 3 + 2] - newxyz[(size_t)sIdx * 3 + 2];
    __syncthreads();

    // ---- layer 1: h1 in registers
    float h1[64];
    const float* f1p = F1 + ((size_t)b * NPTS + p) * 64;
#pragma unroll 4
    for (int c4 = 0; c4 < 16; ++c4) {
        float4 f  = *reinterpret_cast<const float4*>(f1p + c4 * 4);
        float4 wx = *reinterpret_cast<const float4*>(w1s + c4 * 4);
        float4 wy = *reinterpret_cast<const float4*>(w1s + 64 + c4 * 4);
        float4 wz = *reinterpret_cast<const float4*>(w1s + 128 + c4 * 4);
        float4 bb = *reinterpret_cast<const float4*>(b1s + c4 * 4);
        h1[c4 * 4 + 0] = fmaxf(bb.x + f.x + rx * wx.x + ry * wy.x + rz * wz.x, 0.0f);
        h1[c4 * 4 + 1] = fmaxf(bb.y + f.y + rx * wx.y + ry * wy.y + rz * wz.y, 0.0f);
        h1[c4 * 4 + 2] = fmaxf(bb.z + f.z + rx * wx.z + ry * wy.z + rz * wz.z, 0.0f);
        h1[c4 * 4 + 3] = fmaxf(bb.w + f.w + rx * wx.w + ry * wy.w + rz * wz.w, 0.0f);
    }

    // ---- layer 2: h2 in registers, weights via LDS broadcast
    float h2[64];
#pragma unroll
    for (int d4 = 0; d4 < 16; ++d4) {
        float4 bb = *reinterpret_cast<const float4*>(b2s + d4 * 4);
        h2[d4 * 4 + 0] = bb.x; h2[d4 * 4 + 1] = bb.y;
        h2[d4 * 4 + 2] = bb.z; h2[d4 * 4 + 3] = bb.w;
    }
#pragma unroll 4
    for (int c = 0; c < 64; ++c) {
        float a = h1[c];
        const float4* w = reinterpret_cast<const float4*>(w2s + c * 64);
#pragma unroll
        for (int d4 = 0; d4 < 16; ++d4) {
            float4 ww = w[d4];
            h2[d4 * 4 + 0] += a * ww.x;
            h2[d4 * 4 + 1] += a * ww.y;
            h2[d4 * 4 + 2] += a * ww.z;
            h2[d4 * 4 + 3] += a * ww.w;
        }
    }
#pragma unroll
    for (int d = 0; d < 64; ++d) h2[d] = fmaxf(h2[d], 0.0f);

    // ---- layer 3 + relu + max over 32 samples, 4 chunks of 32 channels
    const size_t obase = (size_t)b * 128 * NPOINT + s;
#pragma unroll 1
    for (int ch = 0; ch < 4; ++ch) {
        float acc[32];
#pragma unroll
        for (int j4 = 0; j4 < 8; ++j4) {
            float4 bb = *reinterpret_cast<const float4*>(b3s + ch * 32 + j4 * 4);
            acc[j4 * 4 + 0] = bb.x; acc[j4 * 4 + 1] = bb.y;
            acc[j4 * 4 + 2] = bb.z; acc[j4 * 4 + 3] = bb.w;
        }
#pragma unroll 4
        for (int c = 0; c < 64; ++c) {
            float a = h2[c];
            const float4* w = reinterpret_cast<const float4*>(w3s + c * 128 + ch * 32);
#pragma unroll
            for (int j4 = 0; j4 < 8; ++j4) {
                float4 ww = w[j4];
                acc[j4 * 4 + 0] += a * ww.x;
                acc[j4 * 4 + 1] += a * ww.y;
                acc[j4 * 4 + 2] += a * ww.z;
                acc[j4 * 4 + 3] += a * ww.w;
            }
        }
#pragma unroll
        for (int j = 0; j < 32; ++j) {
            float v = fmaxf(acc[j], 0.0f);
#pragma unroll
            for (int m = 16; m >= 1; m >>= 1) v = fmaxf(v, __shfl_xor(v, m, 64));
            acc[j] = v;
        }
        if (k == 0) {
#pragma unroll
            for (int j = 0; j < 32; ++j)
                outF[obase + (size_t)(ch * 32 + j) * NPOINT] = acc[j];
        }
    }
}

// ---------------------------------------------------------------------------
extern "C" void kernel_launch(void* const* d_in, const int* in_sizes, int n_in,
                              void* d_out, int out_size, void* d_ws, size_t ws_size,
                              hipStream_t stream) {
    const float* xyz      = (const float*)d_in[0];
    const float* features = (const float*)d_in[1];
    const float* W1       = (const float*)d_in[2];
    const float* b1       = (const float*)d_in[3];
    const float* W2       = (const float*)d_in[4];
    const float* b2       = (const float*)d_in[5];
    const float* W3       = (const float*)d_in[6];
    const float* b3       = (const float*)d_in[7];

    float* out_newxyz = (float*)d_out;                                  // B*NPOINT*3 f32
    float* out_feat   = (float*)d_out + (size_t)BATCH * NPOINT * 3;     // B*128*NPOINT f32

    // workspace: ballidx 2MB | F1 16.8MB
    int*   ballidx = (int*)d_ws;
    float* F1      = (float*)((char*)d_ws + (size_t)BATCH * NPOINT * NSAMPLE * 4);

    // fps (blocks 0-7) + f1 (blocks 8-519) fused: f1 hides under fps
    fps_f1_kernel<<<8 + 512, 512, 3 * NPTS * 4, stream>>>(xyz, features, W1, F1, out_newxyz);

    ball_kernel<<<dim3(NPOINT / 64, BATCH), 64, NPTS * 16, stream>>>(xyz, out_newxyz, ballidx);

    mlp_kernel<<<(BATCH * NPOINT) / 8, 256, 0, stream>>>(
        xyz, W1, b1, W2, b2, W3, b3, F1, ballidx, out_newxyz, out_feat);
}

// Round 23
// 2511.754 us; speedup vs baseline: 1.0546x; 1.0546x over previous
//
#include <hip/hip_runtime.h>
#include <cstddef>

#define BATCH 8
#define NPTS 8192
#define NFEAT 64
#define NPOINT 2048
#define NSAMPLE 32

// -- plain-rounded ops, contraction-proof (verified bit-exact R4-R22)
__device__ __forceinline__ float sq_nc(float a) {
    float r = a * a;
    asm volatile("" : "+v"(r));
    return r;
}
__device__ __forceinline__ float mul_nc(float a, float b) {
    float r = a * b;
    asm volatile("" : "+v"(r));
    return r;
}

// DPP-based fmax mix (VALU ~5cyc). Controls: 0xB1 xor1, 0x4E xor2,
// 0x141 row_half_mirror, 0x140 row_mirror, 0x142 bcast15, 0x143 bcast31.
template <int CTRL>
__device__ __forceinline__ float dppmax(float v) {
    int r = __builtin_amdgcn_mov_dpp(__float_as_int(v), CTRL, 0xF, 0xF, true);
    return fmaxf(v, __int_as_float(r));
}

// ---------------------------------------------------------------------------
// FUSED fps + f1 kernel. R21-EXACT (best measured: 1637us steady-state).
// ---------------------------------------------------------------------------
__global__ __launch_bounds__(512) void fps_f1_kernel(const float* __restrict__ xyz,
                                                     const float* __restrict__ features,
                                                     const float* __restrict__ W1,
                                                     float* __restrict__ F1,
                                                     float* __restrict__ newxyz) {
    extern __shared__ float lds[];
    const int tid = threadIdx.x;

    if (blockIdx.x >= 8) {
        // ================= F1 part: 128 points per block =================
        const int lane = tid & 63;
        const int chunk = (tid >> 6) & 3;              // 0..3 (16 ch each)
        const int sub = tid >> 8;                      // 0..1
        const int fblk = blockIdx.x - 8;               // 0..511
        const int b = fblk >> 6;                       // 64 blocks/batch
        const int n = ((fblk & 63) << 7) + (sub << 6) + lane;
        const float* fb = features + (size_t)b * NFEAT * NPTS + n;
        const float* wbase = W1 + 3 * 64 + chunk * 16;

        float acc[16];
#pragma unroll
        for (int i = 0; i < 16; ++i) acc[i] = 0.0f;

#pragma unroll 4
        for (int cp = 0; cp < 64; ++cp) {
            float f = fb[(size_t)cp * NPTS];
            const float4* w = reinterpret_cast<const float4*>(wbase + (size_t)cp * 64);
#pragma unroll
            for (int c4 = 0; c4 < 4; ++c4) {
                float4 ww = w[c4];
                acc[c4 * 4 + 0] += f * ww.x;
                acc[c4 * 4 + 1] += f * ww.y;
                acc[c4 * 4 + 2] += f * ww.z;
                acc[c4 * 4 + 3] += f * ww.w;
            }
        }
        float* o = F1 + ((size_t)b * NPTS + n) * 64 + chunk * 16;
#pragma unroll
        for (int c4 = 0; c4 < 4; ++c4) {
            float4 v;
            v.x = acc[c4 * 4 + 0]; v.y = acc[c4 * 4 + 1];
            v.z = acc[c4 * 4 + 2]; v.w = acc[c4 * 4 + 3];
            *reinterpret_cast<float4*>(o + c4 * 4) = v;
        }
        return;
    }

    // ================= FPS part =================
    float* sx = lds;
    float* sy = lds + NPTS;
    float* sz = lds + 2 * NPTS;
    __shared__ alignas(16) unsigned long long redp[2][8];

    const int b = blockIdx.x;
    const int lane = tid & 63;
    const int wid = tid >> 6;
    const float* xb = xyz + (size_t)b * NPTS * 3;

    for (int i = tid; i < NPTS; i += 512) {
        sx[i] = xb[i * 3 + 0];
        sy[i] = xb[i * 3 + 1];
        sz[i] = xb[i * 3 + 2];
    }
    __syncthreads();

    float mx[16], my_[16], mz[16], md[16];
    const int base = tid * 16;
#pragma unroll
    for (int j = 0; j < 16; ++j) {
        mx[j] = sx[base + j];
        my_[j] = sy[base + j];
        mz[j] = sz[base + j];
        md[j] = INFINITY;
    }

    if (tid == 0) {
        newxyz[(size_t)b * NPOINT * 3 + 0] = sx[0];
        newxyz[(size_t)b * NPOINT * 3 + 1] = sy[0];
        newxyz[(size_t)b * NPOINT * 3 + 2] = sz[0];
    }
    float xl = sx[0], yl = sy[0], zl = sz[0];
    int par = 0;

    for (int it = 1; it < NPOINT; ++it) {
        float bv = -1.0f;
        int bi = 0;
#pragma unroll
        for (int j = 0; j < 16; ++j) {
            float dx = mx[j] - xl;
            float dy = my_[j] - yl;
            float dz = mz[j] - zl;
            float d = (sq_nc(dx) + sq_nc(dy)) + sq_nc(dz);
            float m = fminf(md[j], d);
            md[j] = m;
            if (m > bv) { bv = m; bi = base + j; }
        }

        float wv = bv;
        wv = dppmax<0xB1>(wv);
        wv = dppmax<0x4E>(wv);
        wv = dppmax<0x141>(wv);
        wv = dppmax<0x140>(wv);
        wv = dppmax<0x142>(wv);
        wv = dppmax<0x143>(wv);
        float wvf = __int_as_float(__builtin_amdgcn_readlane(__float_as_int(wv), 63));

        unsigned long long msk = __ballot(bv == wvf);
        int src = __builtin_ctzll(msk);
        if (lane == src)
            redp[par][wid] = ((unsigned long long)__float_as_uint(wvf) << 32) |
                             (unsigned int)(~(unsigned int)bi);
        __syncthreads();

        const ulonglong2* rp = (const ulonglong2*)redp[par];
        ulonglong2 r0 = rp[0], r1 = rp[1], r2 = rp[2], r3 = rp[3];
        unsigned long long m0 = (r0.x > r0.y) ? r0.x : r0.y;
        unsigned long long m1 = (r1.x > r1.y) ? r1.x : r1.y;
        unsigned long long m2 = (r2.x > r2.y) ? r2.x : r2.y;
        unsigned long long m3 = (r3.x > r3.y) ? r3.x : r3.y;
        m0 = (m1 > m0) ? m1 : m0;
        m2 = (m3 > m2) ? m3 : m2;
        m0 = (m2 > m0) ? m2 : m0;
        const int fi = (int)(~(unsigned int)m0);

        xl = sx[fi]; yl = sy[fi]; zl = sz[fi];
        if (tid == 0) {
            size_t o = (size_t)b * NPOINT * 3 + (size_t)it * 3;
            newxyz[o + 0] = xl;
            newxyz[o + 1] = yl;
            newxyz[o + 2] = zl;
        }
        par ^= 1;
    }
}

// ---------------------------------------------------------------------------
// Ball query. UNCHANGED (verified R5-R22).
// ---------------------------------------------------------------------------
__global__ __launch_bounds__(64) void ball_kernel(const float* __restrict__ xyz,
                                                  const float* __restrict__ newxyz,
                                                  int* __restrict__ ballidx) {
    extern __shared__ float4 s4[];                       // 8192 float4 = 128KB
    const int b = blockIdx.y;
    const int s = blockIdx.x * 64 + threadIdx.x;
    const float* xb = xyz + (size_t)b * NPTS * 3;
    for (int i = threadIdx.x; i < NPTS; i += 64) {
        float x = xb[i * 3 + 0], y = xb[i * 3 + 1], z = xb[i * 3 + 2];
        float sq = (sq_nc(x) + sq_nc(y)) + sq_nc(z);
        s4[i] = make_float4(x, y, z, sq);
    }
    __syncthreads();

    const int sIdx = b * NPOINT + s;
    float cx = newxyz[(size_t)sIdx * 3 + 0];
    float cy = newxyz[(size_t)sIdx * 3 + 1];
    float cz = newxyz[(size_t)sIdx * 3 + 2];
    float cq = (sq_nc(cx) + sq_nc(cy)) + sq_nc(cz);

    int* ob = ballidx + (size_t)sIdx * NSAMPLE;
    int cnt = 0;
    int first = 0;
#pragma unroll 4
    for (int n = 0; n < NPTS; ++n) {
        float4 p = s4[n];
        float dot = __fmaf_rn(cz, p.z, __fmaf_rn(cy, p.y, __fmul_rn(cx, p.x)));
        float d2 = (cq + p.w) - mul_nc(2.0f, dot);
        if (d2 < 0.04f && cnt < NSAMPLE) {
            ob[cnt] = n;
            if (cnt == 0) first = n;
            ++cnt;
        }
    }
    for (int j = cnt; j < NSAMPLE; ++j) ob[j] = first;
}

// ---------------------------------------------------------------------------
// Fused grouped-MLP + max-pool. EXACT R7/R13/R21 version (empirically best:
// 2048 blocks x 256 thr, 64KB static hbuf -> 2 blocks/CU = 8 waves/CU,
// weights from global L2-cached wave-uniform loads, rolled unroll-4 loops).
// ---------------------------------------------------------------------------
__global__ __launch_bounds__(256) void mlp_kernel(const float* __restrict__ xyz,
                                                  const float* __restrict__ W1,
                                                  const float* __restrict__ b1,
                                                  const float* __restrict__ W2,
                                                  const float* __restrict__ b2,
                                                  const float* __restrict__ W3,
                                                  const float* __restrict__ b3,
                                                  const float* __restrict__ F1,
                                                  const int* __restrict__ ballidx,
                                                  const float* __restrict__ newxyz,
                                                  float* __restrict__ outF) {
    __shared__ float hbuf[64][256];                    // 64KB static
    const int tid = threadIdx.x;
    const int k = tid & 31;
    const int sIdx = blockIdx.x * 8 + (tid >> 5);      // 0 .. BATCH*NPOINT-1
    const int b = sIdx >> 11;
    const int s = sIdx & (NPOINT - 1);

    const int p = ballidx[(size_t)sIdx * NSAMPLE + k];
    const float* xb = xyz + (size_t)b * NPTS * 3;
    float rx = xb[p * 3 + 0] - newxyz[(size_t)sIdx * 3 + 0];
    float ry = xb[p * 3 + 1] - newxyz[(size_t)sIdx * 3 + 1];
    float rz = xb[p * 3 + 2] - newxyz[(size_t)sIdx * 3 + 2];

    // ---- layer 1 -> LDS column
    const float* f1p = F1 + ((size_t)b * NPTS + p) * 64;
#pragma unroll 4
    for (int c4 = 0; c4 < 16; ++c4) {
        float4 f  = *reinterpret_cast<const float4*>(f1p + c4 * 4);
        float4 wx = *reinterpret_cast<const float4*>(W1 + c4 * 4);
        float4 wy = *reinterpret_cast<const float4*>(W1 + 64 + c4 * 4);
        float4 wz = *reinterpret_cast<const float4*>(W1 + 128 + c4 * 4);
        float4 bb = *reinterpret_cast<const float4*>(b1 + c4 * 4);
        hbuf[c4 * 4 + 0][tid] = fmaxf(bb.x + f.x + rx * wx.x + ry * wy.x + rz * wz.x, 0.0f);
        hbuf[c4 * 4 + 1][tid] = fmaxf(bb.y + f.y + rx * wx.y + ry * wy.y + rz * wz.y, 0.0f);
        hbuf[c4 * 4 + 2][tid] = fmaxf(bb.z + f.z + rx * wx.z + ry * wy.z + rz * wz.z, 0.0f);
        hbuf[c4 * 4 + 3][tid] = fmaxf(bb.w + f.w + rx * wx.w + ry * wy.w + rz * wz.w, 0.0f);
    }

    // ---- layer 2: h2 in regs, h1 read from LDS
    float h2[64];
#pragma unroll
    for (int d4 = 0; d4 < 16; ++d4) {
        float4 bb = *reinterpret_cast<const float4*>(b2 + d4 * 4);
        h2[d4 * 4 + 0] = bb.x; h2[d4 * 4 + 1] = bb.y;
        h2[d4 * 4 + 2] = bb.z; h2[d4 * 4 + 3] = bb.w;
    }
#pragma unroll 4
    for (int c = 0; c < 64; ++c) {
        float a = hbuf[c][tid];
        const float4* w = reinterpret_cast<const float4*>(W2 + (size_t)c * 64);
#pragma unroll
        for (int d4 = 0; d4 < 16; ++d4) {
            float4 ww = w[d4];
            h2[d4 * 4 + 0] += a * ww.x;
            h2[d4 * 4 + 1] += a * ww.y;
            h2[d4 * 4 + 2] += a * ww.z;
            h2[d4 * 4 + 3] += a * ww.w;
        }
    }
    // relu + restage into same LDS columns (h1 dead; own column -> no barrier)
#pragma unroll
    for (int d = 0; d < 64; ++d) hbuf[d][tid] = fmaxf(h2[d], 0.0f);

    // ---- layer 3 + relu + max over 32 samples, 4 chunks of 32 channels
    const size_t obase = (size_t)b * 128 * NPOINT + s;
#pragma unroll 1
    for (int ch = 0; ch < 4; ++ch) {
        float acc[32];
#pragma unroll
        for (int j4 = 0; j4 < 8; ++j4) {
            float4 bb = *reinterpret_cast<const float4*>(b3 + ch * 32 + j4 * 4);
            acc[j4 * 4 + 0] = bb.x; acc[j4 * 4 + 1] = bb.y;
            acc[j4 * 4 + 2] = bb.z; acc[j4 * 4 + 3] = bb.w;
        }
#pragma unroll 4
        for (int c = 0; c < 64; ++c) {
            float a = hbuf[c][tid];
            const float4* w = reinterpret_cast<const float4*>(W3 + (size_t)c * 128 + ch * 32);
#pragma unroll
            for (int j4 = 0; j4 < 8; ++j4) {
                float4 ww = w[j4];
                acc[j4 * 4 + 0] += a * ww.x;
                acc[j4 * 4 + 1] += a * ww.y;
                acc[j4 * 4 + 2] += a * ww.z;
                acc[j4 * 4 + 3] += a * ww.w;
            }
        }
#pragma unroll
        for (int j = 0; j < 32; ++j) {
            float v = fmaxf(acc[j], 0.0f);
#pragma unroll
            for (int m = 16; m >= 1; m >>= 1) v = fmaxf(v, __shfl_xor(v, m, 64));
            acc[j] = v;
        }
        if (k == 0) {
#pragma unroll
            for (int j = 0; j < 32; ++j)
                outF[obase + (size_t)(ch * 32 + j) * NPOINT] = acc[j];
        }
    }
}

// ---------------------------------------------------------------------------
extern "C" void kernel_launch(void* const* d_in, const int* in_sizes, int n_in,
                              void* d_out, int out_size, void* d_ws, size_t ws_size,
                              hipStream_t stream) {
    const float* xyz      = (const float*)d_in[0];
    const float* features = (const float*)d_in[1];
    const float* W1       = (const float*)d_in[2];
    const float* b1       = (const float*)d_in[3];
    const float* W2       = (const float*)d_in[4];
    const float* b2       = (const float*)d_in[5];
    const float* W3       = (const float*)d_in[6];
    const float* b3       = (const float*)d_in[7];

    float* out_newxyz = (float*)d_out;                                  // B*NPOINT*3 f32
    float* out_feat   = (float*)d_out + (size_t)BATCH * NPOINT * 3;     // B*128*NPOINT f32

    // workspace: ballidx 2MB | F1 16.8MB
    int*   ballidx = (int*)d_ws;
    float* F1      = (float*)((char*)d_ws + (size_t)BATCH * NPOINT * NSAMPLE * 4);

    // fps (blocks 0-7) + f1 (blocks 8-519) fused: f1 hides under fps
    fps_f1_kernel<<<8 + 512, 512, 3 * NPTS * 4, stream>>>(xyz, features, W1, F1, out_newxyz);

    ball_kernel<<<dim3(NPOINT / 64, BATCH), 64, NPTS * 16, stream>>>(xyz, out_newxyz, ballidx);

    mlp_kernel<<<(BATCH * NPOINT) / 8, 256, 0, stream>>>(
        xyz, W1, b1, W2, b2, W3, b3, F1, ballidx, out_newxyz, out_feat);
}